// Round 1
// baseline (20883.664 us; speedup 1.0000x reference)
//
#include <hip/hip_runtime.h>

#define NCH 21
#define NPIX (512*512)

__global__ void splat1_kernel(const float* __restrict__ ws, const int* __restrict__ os,
                              float* vals, int npairs) {
  int p = blockIdx.x*blockDim.x + threadIdx.x;
  if (p < npairs) atomicAdd(&vals[os[p]+1], ws[p]);
}

__global__ void blur1_kernel(const float* __restrict__ in, float* __restrict__ out,
                             const int* __restrict__ bn, int M) {
  int i = blockIdx.x*blockDim.x + threadIdx.x;
  if (i < M) {
    int b0 = bn[2*i];
    int b1 = bn[2*i+1];
    out[i+1] = in[i+1] + 0.5f*(in[b0] + in[b1]);
  }
}

__global__ void slice_norm_kernel(const float* __restrict__ ws, const int* __restrict__ os,
                                  const float* __restrict__ vals, float* __restrict__ inv,
                                  int K, float alpha) {
  int n = blockIdx.x*blockDim.x + threadIdx.x;
  if (n >= NPIX) return;
  float s = 0.f;
  for (int j = 0; j < K; ++j) s += ws[n*K+j] * vals[os[n*K+j]+1];
  inv[n] = 1.0f/(alpha*s + 1e-20f);
}

__global__ void softmax_init_kernel(const float* __restrict__ U, float* __restrict__ Q) {
  int n = blockIdx.x*blockDim.x + threadIdx.x;
  if (n >= NPIX) return;
  float l[NCH];
  float m = -3.4e38f;
  #pragma unroll
  for (int c = 0; c < NCH; ++c) { l[c] = -U[(size_t)n*NCH+c]; m = fmaxf(m, l[c]); }
  float s = 0.f;
  #pragma unroll
  for (int c = 0; c < NCH; ++c) { l[c] = expf(l[c]-m); s += l[c]; }
  float r = 1.0f/s;
  #pragma unroll
  for (int c = 0; c < NCH; ++c) Q[(size_t)n*NCH+c] = l[c]*r;
}

template<int K>
__global__ void splatC_kernel(const float* __restrict__ Q, const float* __restrict__ ws,
                              const int* __restrict__ os, float* vals, int npairs) {
  int p = blockIdx.x*blockDim.x + threadIdx.x;
  if (p >= npairs) return;
  int n = p / K;
  float w = ws[p];
  float* dst = vals + (size_t)(os[p]+1)*NCH;
  const float* q = Q + (size_t)n*NCH;
  #pragma unroll
  for (int c = 0; c < NCH; ++c) atomicAdd(&dst[c], w*q[c]);
}

__global__ void blurC_kernel(const float* __restrict__ in, float* __restrict__ out,
                             const int* __restrict__ bn, int M) {
  int t = blockIdx.x*blockDim.x + threadIdx.x;
  if (t >= M*NCH) return;
  int i = t / NCH;
  int c = t - i*NCH;
  int b0 = bn[2*i];
  int b1 = bn[2*i+1];
  out[(size_t)(i+1)*NCH + c] = in[(size_t)(i+1)*NCH + c]
      + 0.5f*(in[(size_t)b0*NCH + c] + in[(size_t)b1*NCH + c]);
}

__global__ void slice_combine_softmax_kernel(
    const float* __restrict__ U,
    const float* __restrict__ vb, const float* __restrict__ vs,
    const float* __restrict__ ws_b, const int* __restrict__ os_b,
    const float* __restrict__ ws_s, const int* __restrict__ os_s,
    const float* __restrict__ inv_nb, const float* __restrict__ inv_ns,
    float* __restrict__ Qout, float scale_b, float scale_s) {
  int n = blockIdx.x*blockDim.x + threadIdx.x;
  if (n >= NPIX) return;
  float l[NCH];
  #pragma unroll
  for (int c = 0; c < NCH; ++c) l[c] = -U[(size_t)n*NCH+c];
  float fb = scale_b * inv_nb[n];
  #pragma unroll
  for (int j = 0; j < 6; ++j) {
    float w = fb * ws_b[n*6+j];
    const float* v = vb + (size_t)(os_b[n*6+j]+1)*NCH;
    #pragma unroll
    for (int c = 0; c < NCH; ++c) l[c] += w*v[c];
  }
  float fs = scale_s * inv_ns[n];
  #pragma unroll
  for (int j = 0; j < 3; ++j) {
    float w = fs * ws_s[n*3+j];
    const float* v = vs + (size_t)(os_s[n*3+j]+1)*NCH;
    #pragma unroll
    for (int c = 0; c < NCH; ++c) l[c] += w*v[c];
  }
  float m = -3.4e38f;
  #pragma unroll
  for (int c = 0; c < NCH; ++c) m = fmaxf(m, l[c]);
  float s = 0.f;
  #pragma unroll
  for (int c = 0; c < NCH; ++c) { l[c] = expf(l[c]-m); s += l[c]; }
  float r = 1.0f/s;
  #pragma unroll
  for (int c = 0; c < NCH; ++c) Qout[(size_t)n*NCH+c] = l[c]*r;
}

extern "C" void kernel_launch(void* const* d_in, const int* in_sizes, int n_in,
                              void* d_out, int out_size, void* d_ws, size_t ws_size,
                              hipStream_t stream) {
  const float* U    = (const float*)d_in[0];
  const float* ws_b = (const float*)d_in[1];
  const float* ws_s = (const float*)d_in[2];
  const int*   os_b = (const int*)d_in[3];
  const int*   os_s = (const int*)d_in[4];
  const int*   bn_b = (const int*)d_in[5];
  const int*   bn_s = (const int*)d_in[6];
  const int Mb = in_sizes[5] / 12;
  const int Ms = in_sizes[6] / 6;

  float* Q      = (float*)d_ws;
  float* vAb    = Q + (size_t)NPIX*NCH;
  float* vBb    = vAb + (size_t)(Mb+1)*NCH;
  float* vAs    = vBb + (size_t)(Mb+1)*NCH;
  float* vBs    = vAs + (size_t)(Ms+1)*NCH;
  float* inv_nb = vBs + (size_t)(Ms+1)*NCH;
  float* inv_ns = inv_nb + NPIX;

  const int TB = 256;
  auto blocks = [](long long n){ return (int)((n + 255)/256); };

  const float a_b = 1.0f/(1.0f + 0.03125f);  // 1/(1+2^-5)
  const float a_s = 1.0f/(1.0f + 0.25f);     // 1/(1+2^-2)

  // ---- normalization, bilateral (C=1; reuse vAb/vBb as scalar buffers) ----
  hipMemsetAsync(vAb, 0, (size_t)(Mb+1)*sizeof(float), stream);
  hipMemsetAsync(vBb, 0, (size_t)(Mb+1)*sizeof(float), stream);
  splat1_kernel<<<blocks((long long)NPIX*6), TB, 0, stream>>>(ws_b, os_b, vAb, NPIX*6);
  {
    float* a = vAb; float* b = vBb;
    for (int j = 0; j < 6; ++j) {
      blur1_kernel<<<blocks(Mb), TB, 0, stream>>>(a, b, bn_b + (size_t)j*Mb*2, Mb);
      float* t = a; a = b; b = t;
    }
    slice_norm_kernel<<<blocks(NPIX), TB, 0, stream>>>(ws_b, os_b, a, inv_nb, 6, a_b);
  }
  // ---- normalization, spatial ----
  hipMemsetAsync(vAs, 0, (size_t)(Ms+1)*sizeof(float), stream);
  hipMemsetAsync(vBs, 0, (size_t)(Ms+1)*sizeof(float), stream);
  splat1_kernel<<<blocks((long long)NPIX*3), TB, 0, stream>>>(ws_s, os_s, vAs, NPIX*3);
  {
    float* a = vAs; float* b = vBs;
    for (int j = 0; j < 3; ++j) {
      blur1_kernel<<<blocks(Ms), TB, 0, stream>>>(a, b, bn_s + (size_t)j*Ms*2, Ms);
      float* t = a; a = b; b = t;
    }
    slice_norm_kernel<<<blocks(NPIX), TB, 0, stream>>>(ws_s, os_s, a, inv_ns, 3, a_s);
  }

  // ---- zero full multichannel buffers (row 0 sentinel + garbage) ----
  hipMemsetAsync(vAb, 0, (size_t)(Mb+1)*NCH*sizeof(float), stream);
  hipMemsetAsync(vBb, 0, (size_t)(Mb+1)*NCH*sizeof(float), stream);
  hipMemsetAsync(vAs, 0, (size_t)(Ms+1)*NCH*sizeof(float), stream);
  hipMemsetAsync(vBs, 0, (size_t)(Ms+1)*NCH*sizeof(float), stream);

  softmax_init_kernel<<<blocks(NPIX), TB, 0, stream>>>(U, Q);

  const float sb = 10.0f * a_b;  // BILATERAL_COMPAT * alpha_b
  const float ss = 3.0f * a_s;   // SPATIAL_COMPAT * alpha_s

  for (int it = 0; it < 5; ++it) {
    if (it > 0) {
      hipMemsetAsync(vAb, 0, (size_t)(Mb+1)*NCH*sizeof(float), stream);
      hipMemsetAsync(vAs, 0, (size_t)(Ms+1)*NCH*sizeof(float), stream);
    }
    // bilateral filter
    splatC_kernel<6><<<blocks((long long)NPIX*6), TB, 0, stream>>>(Q, ws_b, os_b, vAb, NPIX*6);
    float* finb;
    {
      float* a = vAb; float* b = vBb;
      for (int j = 0; j < 6; ++j) {
        blurC_kernel<<<blocks((long long)Mb*NCH), TB, 0, stream>>>(a, b, bn_b + (size_t)j*Mb*2, Mb);
        float* t = a; a = b; b = t;
      }
      finb = a;  // 6 steps -> back in vAb
    }
    // spatial filter
    splatC_kernel<3><<<blocks((long long)NPIX*3), TB, 0, stream>>>(Q, ws_s, os_s, vAs, NPIX*3);
    float* fins;
    {
      float* a = vAs; float* b = vBs;
      for (int j = 0; j < 3; ++j) {
        blurC_kernel<<<blocks((long long)Ms*NCH), TB, 0, stream>>>(a, b, bn_s + (size_t)j*Ms*2, Ms);
        float* t = a; a = b; b = t;
      }
      fins = a;  // 3 steps -> vBs
    }
    float* qdst = (it == 4) ? (float*)d_out : Q;
    slice_combine_softmax_kernel<<<blocks(NPIX), TB, 0, stream>>>(
        U, finb, fins, ws_b, os_b, ws_s, os_s, inv_nb, inv_ns, qdst, sb, ss);
  }
}

// Round 2
// 2020.939 us; speedup vs baseline: 10.3336x; 10.3336x over previous
//
#include <hip/hip_runtime.h>

#define NCH 21
#define QS 24          // padded Q row stride (16B-alignable)
#define NPIX (512*512)

// ---------------- CSR build ----------------

__global__ void count_kernel(const int* __restrict__ os, int* __restrict__ cnt, int npairs) {
  int p = blockIdx.x*blockDim.x + threadIdx.x;
  if (p < npairs) atomicAdd(&cnt[os[p]], 1);
}

__global__ void scan_block_kernel(const int* __restrict__ cnt, int* __restrict__ excl,
                                  int* __restrict__ bsum, int M) {
  __shared__ int s[256];
  int i = blockIdx.x*256 + threadIdx.x;
  int v = (i < M) ? cnt[i] : 0;
  s[threadIdx.x] = v;
  __syncthreads();
  for (int off = 1; off < 256; off <<= 1) {
    int t = (threadIdx.x >= off) ? s[threadIdx.x - off] : 0;
    __syncthreads();
    s[threadIdx.x] += t;
    __syncthreads();
  }
  if (i < M) excl[i] = s[threadIdx.x] - v;
  if (threadIdx.x == 255) bsum[blockIdx.x] = s[255];
}

__global__ void scan_sums_kernel(int* __restrict__ bsum, int nb) {
  __shared__ int s[256];
  __shared__ int carry;
  if (threadIdx.x == 0) carry = 0;
  __syncthreads();
  for (int base = 0; base < nb; base += 256) {
    int i = base + threadIdx.x;
    int v = (i < nb) ? bsum[i] : 0;
    s[threadIdx.x] = v;
    __syncthreads();
    for (int off = 1; off < 256; off <<= 1) {
      int t = (threadIdx.x >= off) ? s[threadIdx.x - off] : 0;
      __syncthreads();
      s[threadIdx.x] += t;
      __syncthreads();
    }
    if (i < nb) bsum[i] = s[threadIdx.x] - v + carry;
    int tot = s[255];
    __syncthreads();
    if (threadIdx.x == 0) carry += tot;
    __syncthreads();
  }
}

__global__ void scan_add_kernel(int* __restrict__ excl, const int* __restrict__ bsum,
                                int M, int npairs) {
  int i = blockIdx.x*blockDim.x + threadIdx.x;
  if (i < M) excl[i] += bsum[i >> 8];
  else if (i == M) excl[M] = npairs;
}

template<int K>
__global__ void fill_kernel(const int* __restrict__ os, const float* __restrict__ ws,
                            const int* __restrict__ start, int* __restrict__ cur,
                            int* __restrict__ pix, float* __restrict__ wv, int npairs) {
  int p = blockIdx.x*blockDim.x + threadIdx.x;
  if (p >= npairs) return;
  int m = os[p];
  int k = start[m] + atomicAdd(&cur[m], 1);
  pix[k] = p / K;
  wv[k] = ws[p];
}

// ---------------- lattice ops ----------------

__global__ void gather_norm_kernel(const int* __restrict__ start, const float* __restrict__ wv,
                                   float* __restrict__ vals, int M) {
  int m = blockIdx.x*blockDim.x + threadIdx.x;
  if (m >= M) return;
  float s = 0.f;
  int k1 = start[m+1];
  for (int k = start[m]; k < k1; ++k) s += wv[k];
  vals[m+1] = s;
}

__global__ void blur1_kernel(const float* __restrict__ in, float* __restrict__ out,
                             const int* __restrict__ bn, int M) {
  int i = blockIdx.x*blockDim.x + threadIdx.x;
  if (i < M) {
    int b0 = bn[2*i];
    int b1 = bn[2*i+1];
    out[i+1] = in[i+1] + 0.5f*(in[b0] + in[b1]);
  }
}

__global__ void slice_norm_kernel(const float* __restrict__ ws, const int* __restrict__ os,
                                  const float* __restrict__ vals, float* __restrict__ inv,
                                  int K, float alpha) {
  int n = blockIdx.x*blockDim.x + threadIdx.x;
  if (n >= NPIX) return;
  float s = 0.f;
  for (int j = 0; j < K; ++j) s += ws[n*K+j] * vals[os[n*K+j]+1];
  inv[n] = 1.0f/(alpha*s + 1e-20f);
}

// gather splat: vals[m+1][c] = sum_k w[k] * Q[pix[k]][c]
__global__ void gatherC_kernel(const float* __restrict__ Q, const int* __restrict__ start,
                               const int* __restrict__ pix, const float* __restrict__ wv,
                               float* __restrict__ vals, int M) {
  int t = blockIdx.x*blockDim.x + threadIdx.x;
  if (t >= M*NCH) return;
  int m = t / NCH;
  int c = t - m*NCH;
  float s = 0.f;
  int k1 = start[m+1];
  for (int k = start[m]; k < k1; ++k)
    s += wv[k] * Q[(size_t)pix[k]*QS + c];
  vals[(size_t)(m+1)*NCH + c] = s;
}

__global__ void blurC_kernel(const float* __restrict__ in, float* __restrict__ out,
                             const int* __restrict__ bn, int M) {
  int t = blockIdx.x*blockDim.x + threadIdx.x;
  if (t >= M*NCH) return;
  int i = t / NCH;
  int c = t - i*NCH;
  int b0 = bn[2*i];
  int b1 = bn[2*i+1];
  out[(size_t)(i+1)*NCH + c] = in[(size_t)(i+1)*NCH + c]
      + 0.5f*(in[(size_t)b0*NCH + c] + in[(size_t)b1*NCH + c]);
}

// ---------------- pixel-side kernels ----------------

__global__ void softmax_init_kernel(const float* __restrict__ U, float* __restrict__ Q) {
  int n = blockIdx.x*blockDim.x + threadIdx.x;
  if (n >= NPIX) return;
  float l[NCH];
  float m = -3.4e38f;
  #pragma unroll
  for (int c = 0; c < NCH; ++c) { l[c] = -U[(size_t)n*NCH+c]; m = fmaxf(m, l[c]); }
  float s = 0.f;
  #pragma unroll
  for (int c = 0; c < NCH; ++c) { l[c] = expf(l[c]-m); s += l[c]; }
  float r = 1.0f/s;
  #pragma unroll
  for (int c = 0; c < NCH; ++c) Q[(size_t)n*QS+c] = l[c]*r;
  #pragma unroll
  for (int c = NCH; c < QS; ++c) Q[(size_t)n*QS+c] = 0.f;
}

template<bool FINAL>
__global__ void slice_combine_softmax_kernel(
    const float* __restrict__ U,
    const float* __restrict__ vb, const float* __restrict__ vs,
    const float* __restrict__ ws_b, const int* __restrict__ os_b,
    const float* __restrict__ ws_s, const int* __restrict__ os_s,
    const float* __restrict__ inv_nb, const float* __restrict__ inv_ns,
    float* __restrict__ Qout, float scale_b, float scale_s) {
  int n = blockIdx.x*blockDim.x + threadIdx.x;
  if (n >= NPIX) return;
  float l[NCH];
  #pragma unroll
  for (int c = 0; c < NCH; ++c) l[c] = -U[(size_t)n*NCH+c];
  float fb = scale_b * inv_nb[n];
  #pragma unroll
  for (int j = 0; j < 6; ++j) {
    float w = fb * ws_b[n*6+j];
    const float* v = vb + (size_t)(os_b[n*6+j]+1)*NCH;
    #pragma unroll
    for (int c = 0; c < NCH; ++c) l[c] += w*v[c];
  }
  float fs = scale_s * inv_ns[n];
  #pragma unroll
  for (int j = 0; j < 3; ++j) {
    float w = fs * ws_s[n*3+j];
    const float* v = vs + (size_t)(os_s[n*3+j]+1)*NCH;
    #pragma unroll
    for (int c = 0; c < NCH; ++c) l[c] += w*v[c];
  }
  float m = -3.4e38f;
  #pragma unroll
  for (int c = 0; c < NCH; ++c) m = fmaxf(m, l[c]);
  float s = 0.f;
  #pragma unroll
  for (int c = 0; c < NCH; ++c) { l[c] = expf(l[c]-m); s += l[c]; }
  float r = 1.0f/s;
  if (FINAL) {
    #pragma unroll
    for (int c = 0; c < NCH; ++c) Qout[(size_t)n*NCH+c] = l[c]*r;
  } else {
    #pragma unroll
    for (int c = 0; c < NCH; ++c) Qout[(size_t)n*QS+c] = l[c]*r;
    #pragma unroll
    for (int c = NCH; c < QS; ++c) Qout[(size_t)n*QS+c] = 0.f;
  }
}

// ---------------- host ----------------

extern "C" void kernel_launch(void* const* d_in, const int* in_sizes, int n_in,
                              void* d_out, int out_size, void* d_ws, size_t ws_size,
                              hipStream_t stream) {
  const float* U    = (const float*)d_in[0];
  const float* ws_b = (const float*)d_in[1];
  const float* ws_s = (const float*)d_in[2];
  const int*   os_b = (const int*)d_in[3];
  const int*   os_s = (const int*)d_in[4];
  const int*   bn_b = (const int*)d_in[5];
  const int*   bn_s = (const int*)d_in[6];
  const int Mb = in_sizes[5] / 12;
  const int Ms = in_sizes[6] / 6;
  const int npb = NPIX*6, nps = NPIX*3;

  // workspace layout
  float* Q      = (float*)d_ws;
  float* vAb    = Q + (size_t)NPIX*QS;
  float* vBb    = vAb + (size_t)(Mb+1)*NCH;
  float* vAs    = vBb + (size_t)(Mb+1)*NCH;
  float* vBs    = vAs + (size_t)(Ms+1)*NCH;
  float* inv_nb = vBs + (size_t)(Ms+1)*NCH;
  float* inv_ns = inv_nb + NPIX;
  int* start_b  = (int*)(inv_ns + NPIX);      // Mb+1
  int* cur_b    = start_b + (Mb+1);           // Mb (counts, then cursor)
  int* start_s  = cur_b + Mb;                 // Ms+1
  int* cur_s    = start_s + (Ms+1);           // Ms
  int* pix_b    = cur_s + Ms;                 // npb
  float* w_b    = (float*)(pix_b + npb);      // npb
  int* pix_s    = (int*)(w_b + npb);          // nps
  float* w_s    = (float*)(pix_s + nps);      // nps
  int* bsum     = (int*)(w_s + nps);          // max scan blocks

  // norm-pass scalar buffers alias the (not yet used) multichannel buffers
  float* nb1a = vAb; float* nb1b = vBb;
  float* ns1a = vAs; float* ns1b = vBs;

  const int TB = 256;
  auto blocks = [](long long n){ return (int)((n + 255)/256); };
  const int nbb = blocks(Mb), nbs = blocks(Ms);

  const float a_b = 1.0f/(1.0f + 0.03125f);  // 1/(1+2^-5)
  const float a_s = 1.0f/(1.0f + 0.25f);     // 1/(1+2^-2)

  // ---- build CSR (both lattices) ----
  hipMemsetAsync(cur_b, 0, (size_t)Mb*sizeof(int), stream);
  hipMemsetAsync(cur_s, 0, (size_t)Ms*sizeof(int), stream);
  count_kernel<<<blocks(npb), TB, 0, stream>>>(os_b, cur_b, npb);
  count_kernel<<<blocks(nps), TB, 0, stream>>>(os_s, cur_s, nps);
  scan_block_kernel<<<nbb, 256, 0, stream>>>(cur_b, start_b, bsum, Mb);
  scan_sums_kernel<<<1, 256, 0, stream>>>(bsum, nbb);
  scan_add_kernel<<<blocks(Mb+1), TB, 0, stream>>>(start_b, bsum, Mb, npb);
  scan_block_kernel<<<nbs, 256, 0, stream>>>(cur_s, start_s, bsum, Ms);
  scan_sums_kernel<<<1, 256, 0, stream>>>(bsum, nbs);
  scan_add_kernel<<<blocks(Ms+1), TB, 0, stream>>>(start_s, bsum, Ms, nps);
  hipMemsetAsync(cur_b, 0, (size_t)Mb*sizeof(int), stream);
  hipMemsetAsync(cur_s, 0, (size_t)Ms*sizeof(int), stream);
  fill_kernel<6><<<blocks(npb), TB, 0, stream>>>(os_b, ws_b, start_b, cur_b, pix_b, w_b, npb);
  fill_kernel<3><<<blocks(nps), TB, 0, stream>>>(os_s, ws_s, start_s, cur_s, pix_s, w_s, nps);

  // ---- normalization (C=1) ----
  hipMemsetAsync(nb1a, 0, sizeof(float), stream);
  hipMemsetAsync(nb1b, 0, sizeof(float), stream);
  hipMemsetAsync(ns1a, 0, sizeof(float), stream);
  hipMemsetAsync(ns1b, 0, sizeof(float), stream);
  gather_norm_kernel<<<nbb, TB, 0, stream>>>(start_b, w_b, nb1a, Mb);
  {
    float* a = nb1a; float* b = nb1b;
    for (int j = 0; j < 6; ++j) {
      blur1_kernel<<<nbb, TB, 0, stream>>>(a, b, bn_b + (size_t)j*Mb*2, Mb);
      float* t = a; a = b; b = t;
    }
    slice_norm_kernel<<<blocks(NPIX), TB, 0, stream>>>(ws_b, os_b, a, inv_nb, 6, a_b);
  }
  gather_norm_kernel<<<nbs, TB, 0, stream>>>(start_s, w_s, ns1a, Ms);
  {
    float* a = ns1a; float* b = ns1b;
    for (int j = 0; j < 3; ++j) {
      blur1_kernel<<<nbs, TB, 0, stream>>>(a, b, bn_s + (size_t)j*Ms*2, Ms);
      float* t = a; a = b; b = t;
    }
    slice_norm_kernel<<<blocks(NPIX), TB, 0, stream>>>(ws_s, os_s, a, inv_ns, 3, a_s);
  }

  // ---- zero sentinel row 0 of multichannel buffers (blur reads index 0 = missing) ----
  hipMemsetAsync(vAb, 0, NCH*sizeof(float), stream);
  hipMemsetAsync(vBb, 0, NCH*sizeof(float), stream);
  hipMemsetAsync(vAs, 0, NCH*sizeof(float), stream);
  hipMemsetAsync(vBs, 0, NCH*sizeof(float), stream);

  softmax_init_kernel<<<blocks(NPIX), TB, 0, stream>>>(U, Q);

  const float sb = 10.0f * a_b;  // BILATERAL_COMPAT * alpha_b
  const float ss = 3.0f * a_s;   // SPATIAL_COMPAT * alpha_s

  for (int it = 0; it < 5; ++it) {
    // bilateral filter (gather splat -> 6 blurs)
    gatherC_kernel<<<blocks((long long)Mb*NCH), TB, 0, stream>>>(Q, start_b, pix_b, w_b, vAb, Mb);
    float* finb;
    {
      float* a = vAb; float* b = vBb;
      for (int j = 0; j < 6; ++j) {
        blurC_kernel<<<blocks((long long)Mb*NCH), TB, 0, stream>>>(a, b, bn_b + (size_t)j*Mb*2, Mb);
        float* t = a; a = b; b = t;
      }
      finb = a;  // even # of steps -> vAb
    }
    // spatial filter
    gatherC_kernel<<<blocks((long long)Ms*NCH), TB, 0, stream>>>(Q, start_s, pix_s, w_s, vAs, Ms);
    float* fins;
    {
      float* a = vAs; float* b = vBs;
      for (int j = 0; j < 3; ++j) {
        blurC_kernel<<<blocks((long long)Ms*NCH), TB, 0, stream>>>(a, b, bn_s + (size_t)j*Ms*2, Ms);
        float* t = a; a = b; b = t;
      }
      fins = a;  // odd # of steps -> vBs
    }
    if (it == 4) {
      slice_combine_softmax_kernel<true><<<blocks(NPIX), TB, 0, stream>>>(
          U, finb, fins, ws_b, os_b, ws_s, os_s, inv_nb, inv_ns, (float*)d_out, sb, ss);
    } else {
      slice_combine_softmax_kernel<false><<<blocks(NPIX), TB, 0, stream>>>(
          U, finb, fins, ws_b, os_b, ws_s, os_s, inv_nb, inv_ns, Q, sb, ss);
    }
  }
}

// Round 3
// 1190.039 us; speedup vs baseline: 17.5487x; 1.6982x over previous
//
#include <hip/hip_runtime.h>

#define NCH 21
#define QS 24          // padded Q row stride (16B-alignable)
#define NPIX (512*512)

// ---------------- CSR build ----------------

__global__ void count_kernel(const int* __restrict__ os, int* __restrict__ cnt, int npairs) {
  int p = blockIdx.x*blockDim.x + threadIdx.x;
  if (p < npairs) atomicAdd(&cnt[os[p]], 1);
}

__global__ void scan_block_kernel(const int* __restrict__ cnt, int* __restrict__ excl,
                                  int* __restrict__ bsum, int M) {
  __shared__ int s[256];
  int i = blockIdx.x*256 + threadIdx.x;
  int v = (i < M) ? cnt[i] : 0;
  s[threadIdx.x] = v;
  __syncthreads();
  for (int off = 1; off < 256; off <<= 1) {
    int t = (threadIdx.x >= off) ? s[threadIdx.x - off] : 0;
    __syncthreads();
    s[threadIdx.x] += t;
    __syncthreads();
  }
  if (i < M) excl[i] = s[threadIdx.x] - v;
  if (threadIdx.x == 255) bsum[blockIdx.x] = s[255];
}

__global__ void scan_sums_kernel(int* __restrict__ bsum, int nb) {
  __shared__ int s[256];
  __shared__ int carry;
  if (threadIdx.x == 0) carry = 0;
  __syncthreads();
  for (int base = 0; base < nb; base += 256) {
    int i = base + threadIdx.x;
    int v = (i < nb) ? bsum[i] : 0;
    s[threadIdx.x] = v;
    __syncthreads();
    for (int off = 1; off < 256; off <<= 1) {
      int t = (threadIdx.x >= off) ? s[threadIdx.x - off] : 0;
      __syncthreads();
      s[threadIdx.x] += t;
      __syncthreads();
    }
    if (i < nb) bsum[i] = s[threadIdx.x] - v + carry;
    int tot = s[255];
    __syncthreads();
    if (threadIdx.x == 0) carry += tot;
    __syncthreads();
  }
}

__global__ void scan_add_kernel(int* __restrict__ excl, const int* __restrict__ bsum,
                                int M, int npairs) {
  int i = blockIdx.x*blockDim.x + threadIdx.x;
  if (i < M) excl[i] += bsum[i >> 8];
  else if (i == M) excl[M] = npairs;
}

// pack (pixel, weight) into one int2 per pair
template<int K>
__global__ void fill_kernel(const int* __restrict__ os, const float* __restrict__ ws,
                            const int* __restrict__ start, int* __restrict__ cur,
                            int2* __restrict__ pw, int npairs) {
  int p = blockIdx.x*blockDim.x + threadIdx.x;
  if (p >= npairs) return;
  int m = os[p];
  int k = start[m] + atomicAdd(&cur[m], 1);
  pw[k] = make_int2(p / K, __float_as_int(ws[p]));
}

// ---------------- lattice ops ----------------

__global__ void gather_norm_kernel(const int* __restrict__ start, const int2* __restrict__ pw,
                                   float* __restrict__ vals, int M) {
  int m = blockIdx.x*blockDim.x + threadIdx.x;
  if (m >= M) return;
  float s = 0.f;
  int k1 = start[m+1];
  for (int k = start[m]; k < k1; ++k) s += __int_as_float(pw[k].y);
  vals[m+1] = s;
}

__global__ void blur1_kernel(const float* __restrict__ in, float* __restrict__ out,
                             const int* __restrict__ bn, int M) {
  int i = blockIdx.x*blockDim.x + threadIdx.x;
  if (i < M) {
    int b0 = bn[2*i];
    int b1 = bn[2*i+1];
    out[i+1] = in[i+1] + 0.5f*(in[b0] + in[b1]);
  }
}

__global__ void slice_norm_kernel(const float* __restrict__ ws, const int* __restrict__ os,
                                  const float* __restrict__ vals, float* __restrict__ inv,
                                  int K, float alpha) {
  int n = blockIdx.x*blockDim.x + threadIdx.x;
  if (n >= NPIX) return;
  float s = 0.f;
  for (int j = 0; j < K; ++j) s += ws[n*K+j] * vals[os[n*K+j]+1];
  inv[n] = 1.0f/(alpha*s + 1e-20f);
}

// gather splat, wave-per-m: lanes = 3 pair-groups x 21 channels, shfl-reduce
__global__ void gather_wave_kernel(const float* __restrict__ Q, const int* __restrict__ start,
                                   const int2* __restrict__ pw, float* __restrict__ vals, int M) {
  int wid = blockIdx.x*(blockDim.x >> 6) + (threadIdx.x >> 6);
  if (wid >= M) return;
  int lane = threadIdx.x & 63;
  int pg = lane / 21;          // 0,1,2 (lane 63 -> 3, idle)
  int c  = lane - pg*21;
  float s = 0.f;
  if (pg < 3) {
    int k  = start[wid] + pg;
    int k1 = start[wid+1];
    for (; k + 3 < k1; k += 6) {
      int2 a = pw[k];
      int2 b = pw[k+3];
      s += __int_as_float(a.y) * Q[(size_t)a.x*QS + c]
         + __int_as_float(b.y) * Q[(size_t)b.x*QS + c];
    }
    if (k < k1) {
      int2 a = pw[k];
      s += __int_as_float(a.y) * Q[(size_t)a.x*QS + c];
    }
  }
  float s1 = __shfl(s, (lane + 21) & 63);
  float s2 = __shfl(s, (lane + 42) & 63);
  if (lane < 21) vals[(size_t)(wid+1)*NCH + c] = s + s1 + s2;
}

__global__ void blurC_kernel(const float* __restrict__ in, float* __restrict__ out,
                             const int* __restrict__ bn, int M) {
  int t = blockIdx.x*blockDim.x + threadIdx.x;
  if (t >= M*NCH) return;
  int i = t / NCH;
  int c = t - i*NCH;
  int b0 = bn[2*i];
  int b1 = bn[2*i+1];
  out[(size_t)(i+1)*NCH + c] = in[(size_t)(i+1)*NCH + c]
      + 0.5f*(in[(size_t)b0*NCH + c] + in[(size_t)b1*NCH + c]);
}

// ---------------- pixel-side kernels ----------------

__global__ void softmax_init_kernel(const float* __restrict__ U, float* __restrict__ Q) {
  int n = blockIdx.x*blockDim.x + threadIdx.x;
  if (n >= NPIX) return;
  float l[NCH];
  float m = -3.4e38f;
  #pragma unroll
  for (int c = 0; c < NCH; ++c) { l[c] = -U[(size_t)n*NCH+c]; m = fmaxf(m, l[c]); }
  float s = 0.f;
  #pragma unroll
  for (int c = 0; c < NCH; ++c) { l[c] = expf(l[c]-m); s += l[c]; }
  float r = 1.0f/s;
  #pragma unroll
  for (int c = 0; c < NCH; ++c) Q[(size_t)n*QS+c] = l[c]*r;
  #pragma unroll
  for (int c = NCH; c < QS; ++c) Q[(size_t)n*QS+c] = 0.f;
}

template<bool FINAL>
__global__ void slice_combine_softmax_kernel(
    const float* __restrict__ U,
    const float* __restrict__ vb, const float* __restrict__ vs,
    const float* __restrict__ ws_b, const int* __restrict__ os_b,
    const float* __restrict__ ws_s, const int* __restrict__ os_s,
    const float* __restrict__ inv_nb, const float* __restrict__ inv_ns,
    float* __restrict__ Qout, float scale_b, float scale_s) {
  int n = blockIdx.x*blockDim.x + threadIdx.x;
  if (n >= NPIX) return;
  float l[NCH];
  #pragma unroll
  for (int c = 0; c < NCH; ++c) l[c] = -U[(size_t)n*NCH+c];
  float fb = scale_b * inv_nb[n];
  #pragma unroll
  for (int j = 0; j < 6; ++j) {
    float w = fb * ws_b[n*6+j];
    const float* v = vb + (size_t)(os_b[n*6+j]+1)*NCH;
    #pragma unroll
    for (int c = 0; c < NCH; ++c) l[c] += w*v[c];
  }
  float fs = scale_s * inv_ns[n];
  #pragma unroll
  for (int j = 0; j < 3; ++j) {
    float w = fs * ws_s[n*3+j];
    const float* v = vs + (size_t)(os_s[n*3+j]+1)*NCH;
    #pragma unroll
    for (int c = 0; c < NCH; ++c) l[c] += w*v[c];
  }
  float m = -3.4e38f;
  #pragma unroll
  for (int c = 0; c < NCH; ++c) m = fmaxf(m, l[c]);
  float s = 0.f;
  #pragma unroll
  for (int c = 0; c < NCH; ++c) { l[c] = expf(l[c]-m); s += l[c]; }
  float r = 1.0f/s;
  if (FINAL) {
    #pragma unroll
    for (int c = 0; c < NCH; ++c) Qout[(size_t)n*NCH+c] = l[c]*r;
  } else {
    #pragma unroll
    for (int c = 0; c < NCH; ++c) Qout[(size_t)n*QS+c] = l[c]*r;
    #pragma unroll
    for (int c = NCH; c < QS; ++c) Qout[(size_t)n*QS+c] = 0.f;
  }
}

// ---------------- host ----------------

extern "C" void kernel_launch(void* const* d_in, const int* in_sizes, int n_in,
                              void* d_out, int out_size, void* d_ws, size_t ws_size,
                              hipStream_t stream) {
  const float* U    = (const float*)d_in[0];
  const float* ws_b = (const float*)d_in[1];
  const float* ws_s = (const float*)d_in[2];
  const int*   os_b = (const int*)d_in[3];
  const int*   os_s = (const int*)d_in[4];
  const int*   bn_b = (const int*)d_in[5];
  const int*   bn_s = (const int*)d_in[6];
  const int Mb = in_sizes[5] / 12;
  const int Ms = in_sizes[6] / 6;
  const int npb = NPIX*6, nps = NPIX*3;

  // workspace layout (16B-aligned chunks)
  char* wcur = (char*)d_ws;
  auto alloc = [&](size_t bytes) -> void* {
    void* p = (void*)wcur;
    wcur += (bytes + 15) & ~(size_t)15;
    return p;
  };
  float* Q      = (float*)alloc((size_t)NPIX*QS*4);
  float* vAb    = (float*)alloc((size_t)(Mb+1)*NCH*4);
  float* vBb    = (float*)alloc((size_t)(Mb+1)*NCH*4);
  float* vAs    = (float*)alloc((size_t)(Ms+1)*NCH*4);
  float* vBs    = (float*)alloc((size_t)(Ms+1)*NCH*4);
  float* inv_nb = (float*)alloc((size_t)NPIX*4);
  float* inv_ns = (float*)alloc((size_t)NPIX*4);
  int*   start_b= (int*)alloc((size_t)(Mb+1)*4);
  int*   cur_b  = (int*)alloc((size_t)Mb*4);
  int*   start_s= (int*)alloc((size_t)(Ms+1)*4);
  int*   cur_s  = (int*)alloc((size_t)Ms*4);
  int2*  pw_b   = (int2*)alloc((size_t)npb*8);
  int2*  pw_s   = (int2*)alloc((size_t)nps*8);
  int*   bsum   = (int*)alloc((size_t)((Mb > Ms ? Mb : Ms)/256 + 2)*4);

  // norm-pass scalar buffers alias the (not yet used) multichannel buffers
  float* nb1a = vAb; float* nb1b = vBb;
  float* ns1a = vAs; float* ns1b = vBs;

  const int TB = 256;
  auto blocks = [](long long n){ return (int)((n + 255)/256); };
  const int nbb = blocks(Mb), nbs = blocks(Ms);

  const float a_b = 1.0f/(1.0f + 0.03125f);  // 1/(1+2^-5)
  const float a_s = 1.0f/(1.0f + 0.25f);     // 1/(1+2^-2)

  // ---- build CSR (both lattices) ----
  hipMemsetAsync(cur_b, 0, (size_t)Mb*sizeof(int), stream);
  hipMemsetAsync(cur_s, 0, (size_t)Ms*sizeof(int), stream);
  count_kernel<<<blocks(npb), TB, 0, stream>>>(os_b, cur_b, npb);
  count_kernel<<<blocks(nps), TB, 0, stream>>>(os_s, cur_s, nps);
  scan_block_kernel<<<nbb, 256, 0, stream>>>(cur_b, start_b, bsum, Mb);
  scan_sums_kernel<<<1, 256, 0, stream>>>(bsum, nbb);
  scan_add_kernel<<<blocks(Mb+1), TB, 0, stream>>>(start_b, bsum, Mb, npb);
  scan_block_kernel<<<nbs, 256, 0, stream>>>(cur_s, start_s, bsum, Ms);
  scan_sums_kernel<<<1, 256, 0, stream>>>(bsum, nbs);
  scan_add_kernel<<<blocks(Ms+1), TB, 0, stream>>>(start_s, bsum, Ms, nps);
  hipMemsetAsync(cur_b, 0, (size_t)Mb*sizeof(int), stream);
  hipMemsetAsync(cur_s, 0, (size_t)Ms*sizeof(int), stream);
  fill_kernel<6><<<blocks(npb), TB, 0, stream>>>(os_b, ws_b, start_b, cur_b, pw_b, npb);
  fill_kernel<3><<<blocks(nps), TB, 0, stream>>>(os_s, ws_s, start_s, cur_s, pw_s, nps);

  // ---- normalization (C=1) ----
  hipMemsetAsync(nb1a, 0, sizeof(float), stream);
  hipMemsetAsync(nb1b, 0, sizeof(float), stream);
  hipMemsetAsync(ns1a, 0, sizeof(float), stream);
  hipMemsetAsync(ns1b, 0, sizeof(float), stream);
  gather_norm_kernel<<<nbb, TB, 0, stream>>>(start_b, pw_b, nb1a, Mb);
  {
    float* a = nb1a; float* b = nb1b;
    for (int j = 0; j < 6; ++j) {
      blur1_kernel<<<nbb, TB, 0, stream>>>(a, b, bn_b + (size_t)j*Mb*2, Mb);
      float* t = a; a = b; b = t;
    }
    slice_norm_kernel<<<blocks(NPIX), TB, 0, stream>>>(ws_b, os_b, a, inv_nb, 6, a_b);
  }
  gather_norm_kernel<<<nbs, TB, 0, stream>>>(start_s, pw_s, ns1a, Ms);
  {
    float* a = ns1a; float* b = ns1b;
    for (int j = 0; j < 3; ++j) {
      blur1_kernel<<<nbs, TB, 0, stream>>>(a, b, bn_s + (size_t)j*Ms*2, Ms);
      float* t = a; a = b; b = t;
    }
    slice_norm_kernel<<<blocks(NPIX), TB, 0, stream>>>(ws_s, os_s, a, inv_ns, 3, a_s);
  }

  // ---- zero sentinel row 0 of multichannel buffers (blur reads index 0 = missing) ----
  hipMemsetAsync(vAb, 0, NCH*sizeof(float), stream);
  hipMemsetAsync(vBb, 0, NCH*sizeof(float), stream);
  hipMemsetAsync(vAs, 0, NCH*sizeof(float), stream);
  hipMemsetAsync(vBs, 0, NCH*sizeof(float), stream);

  softmax_init_kernel<<<blocks(NPIX), TB, 0, stream>>>(U, Q);

  const float sb = 10.0f * a_b;  // BILATERAL_COMPAT * alpha_b
  const float ss = 3.0f * a_s;   // SPATIAL_COMPAT * alpha_s

  for (int it = 0; it < 5; ++it) {
    // bilateral filter (wave-per-m gather -> 6 blurs)
    gather_wave_kernel<<<blocks((long long)Mb*64), TB, 0, stream>>>(Q, start_b, pw_b, vAb, Mb);
    float* finb;
    {
      float* a = vAb; float* b = vBb;
      for (int j = 0; j < 6; ++j) {
        blurC_kernel<<<blocks((long long)Mb*NCH), TB, 0, stream>>>(a, b, bn_b + (size_t)j*Mb*2, Mb);
        float* t = a; a = b; b = t;
      }
      finb = a;  // even # of steps -> vAb
    }
    // spatial filter
    gather_wave_kernel<<<blocks((long long)Ms*64), TB, 0, stream>>>(Q, start_s, pw_s, vAs, Ms);
    float* fins;
    {
      float* a = vAs; float* b = vBs;
      for (int j = 0; j < 3; ++j) {
        blurC_kernel<<<blocks((long long)Ms*NCH), TB, 0, stream>>>(a, b, bn_s + (size_t)j*Ms*2, Ms);
        float* t = a; a = b; b = t;
      }
      fins = a;  // odd # of steps -> vBs
    }
    if (it == 4) {
      slice_combine_softmax_kernel<true><<<blocks(NPIX), TB, 0, stream>>>(
          U, finb, fins, ws_b, os_b, ws_s, os_s, inv_nb, inv_ns, (float*)d_out, sb, ss);
    } else {
      slice_combine_softmax_kernel<false><<<blocks(NPIX), TB, 0, stream>>>(
          U, finb, fins, ws_b, os_b, ws_s, os_s, inv_nb, inv_ns, Q, sb, ss);
    }
  }
}

// Round 4
// 964.274 us; speedup vs baseline: 21.6574x; 1.2341x over previous
//
#include <hip/hip_runtime.h>
#include <hip/hip_fp16.h>

#define NCH 21
#define QSH 32          // Q row stride in halves (64B, line-aligned)
#define NPIX (512*512)  // 2^18

// ---------------- unified CSR build ----------------

__global__ void count_fused_kernel(const int* __restrict__ os_b, const int* __restrict__ os_s,
                                   int* __restrict__ cnt, int npb, int nptot, int Mb) {
  int t = blockIdx.x*blockDim.x + threadIdx.x;
  if (t >= nptot) return;
  int m = (t < npb) ? os_b[t] : (Mb + os_s[t - npb]);
  atomicAdd(&cnt[m], 1);
}

__global__ void scan_block_kernel(const int* __restrict__ cnt, int* __restrict__ excl,
                                  int* __restrict__ bsum, int M) {
  __shared__ int s[256];
  int i = blockIdx.x*256 + threadIdx.x;
  int v = (i < M) ? cnt[i] : 0;
  s[threadIdx.x] = v;
  __syncthreads();
  for (int off = 1; off < 256; off <<= 1) {
    int t = (threadIdx.x >= off) ? s[threadIdx.x - off] : 0;
    __syncthreads();
    s[threadIdx.x] += t;
    __syncthreads();
  }
  if (i < M) excl[i] = s[threadIdx.x] - v;
  if (threadIdx.x == 255) bsum[blockIdx.x] = s[255];
}

__global__ void scan_sums_kernel(int* __restrict__ bsum, int nb) {
  __shared__ int s[256];
  __shared__ int carry;
  if (threadIdx.x == 0) carry = 0;
  __syncthreads();
  for (int base = 0; base < nb; base += 256) {
    int i = base + threadIdx.x;
    int v = (i < nb) ? bsum[i] : 0;
    s[threadIdx.x] = v;
    __syncthreads();
    for (int off = 1; off < 256; off <<= 1) {
      int t = (threadIdx.x >= off) ? s[threadIdx.x - off] : 0;
      __syncthreads();
      s[threadIdx.x] += t;
      __syncthreads();
    }
    if (i < nb) bsum[i] = s[threadIdx.x] - v + carry;
    int tot = s[255];
    __syncthreads();
    if (threadIdx.x == 0) carry += tot;
    __syncthreads();
  }
}

__global__ void scan_add_kernel(int* __restrict__ excl, const int* __restrict__ bsum,
                                int M, int nptot) {
  int i = blockIdx.x*blockDim.x + threadIdx.x;
  if (i < M) excl[i] += bsum[i >> 8];
  else if (i == M) excl[M] = nptot;
}

// pack (pixel<<14 | w14) into one uint per pair; w in [0,1] -> 14-bit fixed point
__global__ void fill_fused_kernel(const int* __restrict__ os_b, const float* __restrict__ ws_b,
                                  const int* __restrict__ os_s, const float* __restrict__ ws_s,
                                  const int* __restrict__ start, int* __restrict__ cur,
                                  unsigned int* __restrict__ pw, int npb, int nptot, int Mb) {
  int t = blockIdx.x*blockDim.x + threadIdx.x;
  if (t >= nptot) return;
  int m, pix; float w;
  if (t < npb) { m = os_b[t]; pix = t / 6; w = ws_b[t]; }
  else { int t2 = t - npb; m = Mb + os_s[t2]; pix = t2 / 3; w = ws_s[t2]; }
  int w14 = (int)(w * 16383.f + 0.5f);
  w14 = w14 < 0 ? 0 : (w14 > 16383 ? 16383 : w14);
  int k = start[m] + atomicAdd(&cur[m], 1);
  pw[k] = ((unsigned int)pix << 14) | (unsigned int)w14;
}

// ---------------- lattice ops ----------------

__global__ void gather_norm_kernel(const int* __restrict__ start, const unsigned int* __restrict__ pw,
                                   float* __restrict__ normB, float* __restrict__ normS,
                                   int Mb, int Mtot) {
  int m = blockIdx.x*blockDim.x + threadIdx.x;
  if (m >= Mtot) return;
  float s = 0.f;
  int k1 = start[m+1];
  for (int k = start[m]; k < k1; ++k) s += (float)(pw[k] & 16383u);
  s *= (1.0f/16383.f);
  if (m < Mb) normB[m+1] = s;
  else normS[m-Mb+1] = s;
}

__global__ void blur1_fused_kernel(const float* __restrict__ inB, float* __restrict__ outB,
                                   const int* __restrict__ bnB, int Mb,
                                   const float* __restrict__ inS, float* __restrict__ outS,
                                   const int* __restrict__ bnS, int Ms) {
  int i = blockIdx.x*blockDim.x + threadIdx.x;
  if (i < Mb) {
    outB[i+1] = inB[i+1] + 0.5f*(inB[bnB[2*i]] + inB[bnB[2*i+1]]);
  } else {
    int j = i - Mb;
    if (j < Ms) outS[j+1] = inS[j+1] + 0.5f*(inS[bnS[2*j]] + inS[bnS[2*j+1]]);
  }
}

__global__ void slice_norm_fused_kernel(const float* __restrict__ ws_b, const int* __restrict__ os_b,
                                        const float* __restrict__ ws_s, const int* __restrict__ os_s,
                                        const float* __restrict__ normB, const float* __restrict__ normS,
                                        float* __restrict__ inv_nb, float* __restrict__ inv_ns,
                                        float alpha_b, float alpha_s) {
  int n = blockIdx.x*blockDim.x + threadIdx.x;
  if (n >= NPIX) return;
  float sb = 0.f;
  #pragma unroll
  for (int j = 0; j < 6; ++j) sb += ws_b[n*6+j] * normB[os_b[n*6+j]+1];
  float ss = 0.f;
  #pragma unroll
  for (int j = 0; j < 3; ++j) ss += ws_s[n*3+j] * normS[os_s[n*3+j]+1];
  inv_nb[n] = 1.0f/(alpha_b*sb + 1e-20f);
  inv_ns[n] = 1.0f/(alpha_s*ss + 1e-20f);
}

// fused gather splat, wave-per-lattice-point: 3 pair-groups x 21 channels + shfl reduce
__global__ void gather_wave_kernel(const __half* __restrict__ Qh, const int* __restrict__ start,
                                   const unsigned int* __restrict__ pw,
                                   float* __restrict__ valsB, float* __restrict__ valsS,
                                   int Mb, int Mtot) {
  int wid = blockIdx.x*(blockDim.x >> 6) + (threadIdx.x >> 6);
  if (wid >= Mtot) return;
  int lane = threadIdx.x & 63;
  int pg = lane / 21;          // 0,1,2 (lane 63 idle)
  int c  = lane - pg*21;
  float s = 0.f;
  int k1 = start[wid+1];
  if (pg < 3) {
    int k = start[wid] + pg;
    for (; k + 3 < k1; k += 6) {
      unsigned int a = pw[k], b = pw[k+3];
      s += (float)(a & 16383u) * __half2float(Qh[((size_t)(a >> 14) << 5) + c])
         + (float)(b & 16383u) * __half2float(Qh[((size_t)(b >> 14) << 5) + c]);
    }
    if (k < k1) {
      unsigned int a = pw[k];
      s += (float)(a & 16383u) * __half2float(Qh[((size_t)(a >> 14) << 5) + c]);
    }
  }
  s *= (1.0f/16383.f);
  float s1 = __shfl(s, (lane + 21) & 63);
  float s2 = __shfl(s, (lane + 42) & 63);
  if (lane < 21) {
    float tot = s + s1 + s2;
    if (wid < Mb) valsB[(size_t)(wid+1)*NCH + c] = tot;
    else          valsS[(size_t)(wid-Mb+1)*NCH + c] = tot;
  }
}

__global__ void blurC_fused_kernel(const float* __restrict__ inB, float* __restrict__ outB,
                                   const int* __restrict__ bnB, int Mb,
                                   const float* __restrict__ inS, float* __restrict__ outS,
                                   const int* __restrict__ bnS, int Ms) {
  int t = blockIdx.x*blockDim.x + threadIdx.x;
  if (t < Mb*NCH) {
    int i = t/NCH, c = t - i*NCH;
    outB[(size_t)(i+1)*NCH+c] = inB[(size_t)(i+1)*NCH+c]
        + 0.5f*(inB[(size_t)bnB[2*i]*NCH+c] + inB[(size_t)bnB[2*i+1]*NCH+c]);
  } else {
    int t2 = t - Mb*NCH;
    if (t2 < Ms*NCH) {
      int i = t2/NCH, c = t2 - i*NCH;
      outS[(size_t)(i+1)*NCH+c] = inS[(size_t)(i+1)*NCH+c]
          + 0.5f*(inS[(size_t)bnS[2*i]*NCH+c] + inS[(size_t)bnS[2*i+1]*NCH+c]);
    }
  }
}

// ---------------- pixel-side kernels ----------------

__global__ void softmax_init_kernel(const float* __restrict__ U, __half* __restrict__ Qh) {
  int n = blockIdx.x*blockDim.x + threadIdx.x;
  if (n >= NPIX) return;
  float l[NCH];
  float m = -3.4e38f;
  #pragma unroll
  for (int c = 0; c < NCH; ++c) { l[c] = -U[(size_t)n*NCH+c]; m = fmaxf(m, l[c]); }
  float s = 0.f;
  #pragma unroll
  for (int c = 0; c < NCH; ++c) { l[c] = expf(l[c]-m); s += l[c]; }
  float r = 1.0f/s;
  #pragma unroll
  for (int c = 0; c < NCH; ++c) Qh[(size_t)n*QSH+c] = __float2half(l[c]*r);
}

template<bool FINAL>
__global__ void slice_combine_softmax_kernel(
    const float* __restrict__ U,
    const float* __restrict__ vb, const float* __restrict__ vs,
    const float* __restrict__ ws_b, const int* __restrict__ os_b,
    const float* __restrict__ ws_s, const int* __restrict__ os_s,
    const float* __restrict__ inv_nb, const float* __restrict__ inv_ns,
    float* __restrict__ QoutF, __half* __restrict__ QoutH,
    float scale_b, float scale_s) {
  int n = blockIdx.x*blockDim.x + threadIdx.x;
  if (n >= NPIX) return;
  float l[NCH];
  #pragma unroll
  for (int c = 0; c < NCH; ++c) l[c] = -U[(size_t)n*NCH+c];
  float fb = scale_b * inv_nb[n];
  #pragma unroll
  for (int j = 0; j < 6; ++j) {
    float w = fb * ws_b[n*6+j];
    const float* v = vb + (size_t)(os_b[n*6+j]+1)*NCH;
    #pragma unroll
    for (int c = 0; c < NCH; ++c) l[c] += w*v[c];
  }
  float fs = scale_s * inv_ns[n];
  #pragma unroll
  for (int j = 0; j < 3; ++j) {
    float w = fs * ws_s[n*3+j];
    const float* v = vs + (size_t)(os_s[n*3+j]+1)*NCH;
    #pragma unroll
    for (int c = 0; c < NCH; ++c) l[c] += w*v[c];
  }
  float m = -3.4e38f;
  #pragma unroll
  for (int c = 0; c < NCH; ++c) m = fmaxf(m, l[c]);
  float s = 0.f;
  #pragma unroll
  for (int c = 0; c < NCH; ++c) { l[c] = expf(l[c]-m); s += l[c]; }
  float r = 1.0f/s;
  if (FINAL) {
    #pragma unroll
    for (int c = 0; c < NCH; ++c) QoutF[(size_t)n*NCH+c] = l[c]*r;
  } else {
    #pragma unroll
    for (int c = 0; c < NCH; ++c) QoutH[(size_t)n*QSH+c] = __float2half(l[c]*r);
  }
}

// ---------------- host ----------------

extern "C" void kernel_launch(void* const* d_in, const int* in_sizes, int n_in,
                              void* d_out, int out_size, void* d_ws, size_t ws_size,
                              hipStream_t stream) {
  const float* U    = (const float*)d_in[0];
  const float* ws_b = (const float*)d_in[1];
  const float* ws_s = (const float*)d_in[2];
  const int*   os_b = (const int*)d_in[3];
  const int*   os_s = (const int*)d_in[4];
  const int*   bn_b = (const int*)d_in[5];
  const int*   bn_s = (const int*)d_in[6];
  const int Mb = in_sizes[5] / 12;
  const int Ms = in_sizes[6] / 6;
  const int Mtot = Mb + Ms;
  const int npb = NPIX*6, nps = NPIX*3;
  const int nptot = npb + nps;

  // workspace layout (16B-aligned chunks)
  char* wcur = (char*)d_ws;
  auto alloc = [&](size_t bytes) -> void* {
    void* p = (void*)wcur;
    wcur += (bytes + 15) & ~(size_t)15;
    return p;
  };
  __half* Qh    = (__half*)alloc((size_t)NPIX*QSH*2);
  float* vAb    = (float*)alloc((size_t)(Mb+1)*NCH*4);
  float* vBb    = (float*)alloc((size_t)(Mb+1)*NCH*4);
  float* vAs    = (float*)alloc((size_t)(Ms+1)*NCH*4);
  float* vBs    = (float*)alloc((size_t)(Ms+1)*NCH*4);
  float* inv_nb = (float*)alloc((size_t)NPIX*4);
  float* inv_ns = (float*)alloc((size_t)NPIX*4);
  int*   start  = (int*)alloc((size_t)(Mtot+1)*4);
  int*   cur    = (int*)alloc((size_t)Mtot*4);
  unsigned int* pw = (unsigned int*)alloc((size_t)nptot*4);
  int*   bsum   = (int*)alloc((size_t)(Mtot/256 + 2)*4);

  // norm-pass scalar fp32 buffers alias the (not yet used) multichannel buffers
  float* nb1a = vAb; float* nb1b = vAb + (Mb+1);
  float* ns1a = vAs; float* ns1b = vAs + (Ms+1);

  const int TB = 256;
  auto blocks = [](long long n){ return (int)((n + 255)/256); };

  const float a_b = 1.0f/(1.0f + 0.03125f);  // 1/(1+2^-5)
  const float a_s = 1.0f/(1.0f + 0.25f);     // 1/(1+2^-2)

  // ---- build unified CSR ----
  hipMemsetAsync(cur, 0, (size_t)Mtot*sizeof(int), stream);
  count_fused_kernel<<<blocks(nptot), TB, 0, stream>>>(os_b, os_s, cur, npb, nptot, Mb);
  scan_block_kernel<<<blocks(Mtot), 256, 0, stream>>>(cur, start, bsum, Mtot);
  scan_sums_kernel<<<1, 256, 0, stream>>>(bsum, blocks(Mtot));
  scan_add_kernel<<<blocks(Mtot+1), TB, 0, stream>>>(start, bsum, Mtot, nptot);
  hipMemsetAsync(cur, 0, (size_t)Mtot*sizeof(int), stream);
  fill_fused_kernel<<<blocks(nptot), TB, 0, stream>>>(os_b, ws_b, os_s, ws_s,
                                                      start, cur, pw, npb, nptot, Mb);

  // ---- normalization (C=1, fp32) ----
  hipMemsetAsync(nb1a, 0, sizeof(float), stream);
  hipMemsetAsync(nb1b, 0, sizeof(float), stream);
  hipMemsetAsync(ns1a, 0, sizeof(float), stream);
  hipMemsetAsync(ns1b, 0, sizeof(float), stream);
  gather_norm_kernel<<<blocks(Mtot), TB, 0, stream>>>(start, pw, nb1a, ns1a, Mb, Mtot);
  {
    float* ab = nb1a; float* bb = nb1b;
    float* as = ns1a; float* bs = ns1b;
    for (int j = 0; j < 6; ++j) {
      int ms = (j < 3) ? Ms : 0;
      blur1_fused_kernel<<<blocks(Mb + ms), TB, 0, stream>>>(
          ab, bb, bn_b + (size_t)j*Mb*2, Mb, as, bs, bn_s + (size_t)j*Ms*2, ms);
      { float* t = ab; ab = bb; bb = t; }
      if (j < 3) { float* t = as; as = bs; bs = t; }
    }
    slice_norm_fused_kernel<<<blocks(NPIX), TB, 0, stream>>>(
        ws_b, os_b, ws_s, os_s, ab, as, inv_nb, inv_ns, a_b, a_s);
  }

  // ---- zero sentinel row 0 of multichannel buffers ----
  hipMemsetAsync(vAb, 0, NCH*sizeof(float), stream);
  hipMemsetAsync(vBb, 0, NCH*sizeof(float), stream);
  hipMemsetAsync(vAs, 0, NCH*sizeof(float), stream);
  hipMemsetAsync(vBs, 0, NCH*sizeof(float), stream);

  softmax_init_kernel<<<blocks(NPIX), TB, 0, stream>>>(U, Qh);

  const float sb = 10.0f * a_b;  // BILATERAL_COMPAT * alpha_b
  const float ss = 3.0f * a_s;   // SPATIAL_COMPAT * alpha_s

  for (int it = 0; it < 5; ++it) {
    // fused gather splat (both lattices), wave per lattice point
    gather_wave_kernel<<<blocks((long long)Mtot*64), TB, 0, stream>>>(
        Qh, start, pw, vAb, vAs, Mb, Mtot);
    // fused blur chain: bilateral 6 steps, spatial first 3
    float* ab = vAb; float* bb = vBb;
    float* as = vAs; float* bs = vBs;
    for (int j = 0; j < 6; ++j) {
      int ms = (j < 3) ? Ms : 0;
      blurC_fused_kernel<<<blocks((long long)(Mb + ms)*NCH), TB, 0, stream>>>(
          ab, bb, bn_b + (size_t)j*Mb*2, Mb, as, bs, bn_s + (size_t)j*Ms*2, ms);
      { float* t = ab; ab = bb; bb = t; }
      if (j < 3) { float* t = as; as = bs; bs = t; }
    }
    // ab = final bilateral (vAb), as = final spatial (vBs)
    if (it == 4) {
      slice_combine_softmax_kernel<true><<<blocks(NPIX), TB, 0, stream>>>(
          U, ab, as, ws_b, os_b, ws_s, os_s, inv_nb, inv_ns,
          (float*)d_out, (__half*)nullptr, sb, ss);
    } else {
      slice_combine_softmax_kernel<false><<<blocks(NPIX), TB, 0, stream>>>(
          U, ab, as, ws_b, os_b, ws_s, os_s, inv_nb, inv_ns,
          (float*)nullptr, Qh, sb, ss);
    }
  }
}

// Round 5
// 631.182 us; speedup vs baseline: 33.0866x; 1.5277x over previous
//
#include <hip/hip_runtime.h>
#include <hip/hip_fp16.h>

#define NCH 21
#define QSH 32          // Q row stride in halves (64B, line-aligned)
#define NPIX (512*512)  // 2^18

// ---------------- wave-aggregated atomic rank ----------------
// For each lane with `valid`, compute slot = cur[m]-base + rank among equal-m
// lanes, using ONE atomicAdd per distinct m per wave. All lanes must execute.
// Returns base+rank for valid lanes (undefined for invalid).
__device__ __forceinline__ int wave_rank_atomic(int m, bool valid, int* __restrict__ cur) {
  int lane = threadIdx.x & 63;
  unsigned long long todo = __ballot(valid);
  int out = 0;
  while (todo) {
    int leader = __ffsll((unsigned long long)todo) - 1;
    int lm = __shfl(m, leader);
    unsigned long long match = __ballot(valid && (m == lm));
    int cnt = __popcll(match);
    int b = 0;
    if (lane == leader) b = atomicAdd(&cur[lm], cnt);
    b = __shfl(b, leader);
    if (valid && (m == lm)) {
      int rank = __popcll(match & ((1ull << lane) - 1ull));
      out = b + rank;
    }
    todo &= ~match;
  }
  return out;
}

// ---------------- unified CSR build ----------------

__global__ void count_fused_kernel(const int* __restrict__ os_b, const int* __restrict__ os_s,
                                   int* __restrict__ cnt, int npb, int nptot, int Mb) {
  int t = blockIdx.x*blockDim.x + threadIdx.x;
  bool valid = (t < nptot);
  int m = 0;
  if (valid) m = (t < npb) ? os_b[t] : (Mb + os_s[t - npb]);
  // wave-aggregated count: one atomic per distinct m per wave
  int lane = threadIdx.x & 63;
  unsigned long long todo = __ballot(valid);
  while (todo) {
    int leader = __ffsll((unsigned long long)todo) - 1;
    int lm = __shfl(m, leader);
    unsigned long long match = __ballot(valid && (m == lm));
    if (lane == leader) atomicAdd(&cnt[lm], __popcll(match));
    todo &= ~match;
  }
}

__global__ void scan_block_kernel(const int* __restrict__ cnt, int* __restrict__ excl,
                                  int* __restrict__ bsum, int M) {
  __shared__ int s[256];
  int i = blockIdx.x*256 + threadIdx.x;
  int v = (i < M) ? cnt[i] : 0;
  s[threadIdx.x] = v;
  __syncthreads();
  for (int off = 1; off < 256; off <<= 1) {
    int t = (threadIdx.x >= off) ? s[threadIdx.x - off] : 0;
    __syncthreads();
    s[threadIdx.x] += t;
    __syncthreads();
  }
  if (i < M) excl[i] = s[threadIdx.x] - v;
  if (threadIdx.x == 255) bsum[blockIdx.x] = s[255];
}

__global__ void scan_sums_kernel(int* __restrict__ bsum, int nb) {
  __shared__ int s[256];
  __shared__ int carry;
  if (threadIdx.x == 0) carry = 0;
  __syncthreads();
  for (int base = 0; base < nb; base += 256) {
    int i = base + threadIdx.x;
    int v = (i < nb) ? bsum[i] : 0;
    s[threadIdx.x] = v;
    __syncthreads();
    for (int off = 1; off < 256; off <<= 1) {
      int t = (threadIdx.x >= off) ? s[threadIdx.x - off] : 0;
      __syncthreads();
      s[threadIdx.x] += t;
      __syncthreads();
    }
    if (i < nb) bsum[i] = s[threadIdx.x] - v + carry;
    int tot = s[255];
    __syncthreads();
    if (threadIdx.x == 0) carry += tot;
    __syncthreads();
  }
}

__global__ void scan_add_kernel(int* __restrict__ excl, const int* __restrict__ bsum,
                                int M, int nptot) {
  int i = blockIdx.x*blockDim.x + threadIdx.x;
  if (i < M) excl[i] += bsum[i >> 8];
  else if (i == M) excl[M] = nptot;
}

// pack (pixel<<14 | w14) into one uint per pair; w in [0,1] -> 14-bit fixed point
__global__ void fill_fused_kernel(const int* __restrict__ os_b, const float* __restrict__ ws_b,
                                  const int* __restrict__ os_s, const float* __restrict__ ws_s,
                                  const int* __restrict__ start, int* __restrict__ cur,
                                  unsigned int* __restrict__ pw, int npb, int nptot, int Mb) {
  int t = blockIdx.x*blockDim.x + threadIdx.x;
  bool valid = (t < nptot);
  int m = 0, pix = 0; float w = 0.f;
  if (valid) {
    if (t < npb) { m = os_b[t]; pix = t / 6; w = ws_b[t]; }
    else { int t2 = t - npb; m = Mb + os_s[t2]; pix = t2 / 3; w = ws_s[t2]; }
  }
  int slot = wave_rank_atomic(m, valid, cur);
  if (valid) {
    int w14 = (int)(w * 16383.f + 0.5f);
    w14 = w14 < 0 ? 0 : (w14 > 16383 ? 16383 : w14);
    pw[start[m] + slot] = ((unsigned int)pix << 14) | (unsigned int)w14;
  }
}

// ---------------- lattice ops ----------------

__global__ void gather_norm_kernel(const int* __restrict__ start, const unsigned int* __restrict__ pw,
                                   float* __restrict__ normB, float* __restrict__ normS,
                                   int Mb, int Mtot) {
  int m = blockIdx.x*blockDim.x + threadIdx.x;
  if (m >= Mtot) return;
  float s = 0.f;
  int k1 = start[m+1];
  for (int k = start[m]; k < k1; ++k) s += (float)(pw[k] & 16383u);
  s *= (1.0f/16383.f);
  if (m < Mb) normB[m+1] = s;
  else normS[m-Mb+1] = s;
}

__global__ void blur1_fused_kernel(const float* __restrict__ inB, float* __restrict__ outB,
                                   const int* __restrict__ bnB, int Mb,
                                   const float* __restrict__ inS, float* __restrict__ outS,
                                   const int* __restrict__ bnS, int Ms) {
  int i = blockIdx.x*blockDim.x + threadIdx.x;
  if (i < Mb) {
    outB[i+1] = inB[i+1] + 0.5f*(inB[bnB[2*i]] + inB[bnB[2*i+1]]);
  } else {
    int j = i - Mb;
    if (j < Ms) outS[j+1] = inS[j+1] + 0.5f*(inS[bnS[2*j]] + inS[bnS[2*j+1]]);
  }
}

__global__ void slice_norm_fused_kernel(const float* __restrict__ ws_b, const int* __restrict__ os_b,
                                        const float* __restrict__ ws_s, const int* __restrict__ os_s,
                                        const float* __restrict__ normB, const float* __restrict__ normS,
                                        float* __restrict__ inv_nb, float* __restrict__ inv_ns,
                                        float alpha_b, float alpha_s) {
  int n = blockIdx.x*blockDim.x + threadIdx.x;
  if (n >= NPIX) return;
  float sb = 0.f;
  #pragma unroll
  for (int j = 0; j < 6; ++j) sb += ws_b[n*6+j] * normB[os_b[n*6+j]+1];
  float ss = 0.f;
  #pragma unroll
  for (int j = 0; j < 3; ++j) ss += ws_s[n*3+j] * normS[os_s[n*3+j]+1];
  inv_nb[n] = 1.0f/(alpha_b*sb + 1e-20f);
  inv_ns[n] = 1.0f/(alpha_s*ss + 1e-20f);
}

// fused gather splat, wave-per-lattice-point: 3 pair-groups x 21 channels + shfl reduce
// 4-deep unroll per group -> up to 12 scattered Q-line loads in flight per wave
__global__ void gather_wave_kernel(const __half* __restrict__ Qh, const int* __restrict__ start,
                                   const unsigned int* __restrict__ pw,
                                   float* __restrict__ valsB, float* __restrict__ valsS,
                                   int Mb, int Mtot) {
  int wid = blockIdx.x*(blockDim.x >> 6) + (threadIdx.x >> 6);
  if (wid >= Mtot) return;
  int lane = threadIdx.x & 63;
  int pg = lane / 21;          // 0,1,2 (lane 63 idle)
  int c  = lane - pg*21;
  float s = 0.f;
  int k1 = start[wid+1];
  if (pg < 3) {
    int k = start[wid] + pg;
    for (; k + 9 < k1; k += 12) {
      unsigned int a0 = pw[k], a1 = pw[k+3], a2 = pw[k+6], a3 = pw[k+9];
      s += (float)(a0 & 16383u) * __half2float(Qh[((size_t)(a0 >> 14) << 5) + c])
         + (float)(a1 & 16383u) * __half2float(Qh[((size_t)(a1 >> 14) << 5) + c])
         + (float)(a2 & 16383u) * __half2float(Qh[((size_t)(a2 >> 14) << 5) + c])
         + (float)(a3 & 16383u) * __half2float(Qh[((size_t)(a3 >> 14) << 5) + c]);
    }
    for (; k < k1; k += 3) {
      unsigned int a = pw[k];
      s += (float)(a & 16383u) * __half2float(Qh[((size_t)(a >> 14) << 5) + c]);
    }
  }
  s *= (1.0f/16383.f);
  float s1 = __shfl(s, (lane + 21) & 63);
  float s2 = __shfl(s, (lane + 42) & 63);
  if (lane < 21) {
    float tot = s + s1 + s2;
    if (wid < Mb) valsB[(size_t)(wid+1)*NCH + c] = tot;
    else          valsS[(size_t)(wid-Mb+1)*NCH + c] = tot;
  }
}

__global__ void blurC_fused_kernel(const float* __restrict__ inB, float* __restrict__ outB,
                                   const int* __restrict__ bnB, int Mb,
                                   const float* __restrict__ inS, float* __restrict__ outS,
                                   const int* __restrict__ bnS, int Ms) {
  int t = blockIdx.x*blockDim.x + threadIdx.x;
  if (t < Mb*NCH) {
    int i = t/NCH, c = t - i*NCH;
    outB[(size_t)(i+1)*NCH+c] = inB[(size_t)(i+1)*NCH+c]
        + 0.5f*(inB[(size_t)bnB[2*i]*NCH+c] + inB[(size_t)bnB[2*i+1]*NCH+c]);
  } else {
    int t2 = t - Mb*NCH;
    if (t2 < Ms*NCH) {
      int i = t2/NCH, c = t2 - i*NCH;
      outS[(size_t)(i+1)*NCH+c] = inS[(size_t)(i+1)*NCH+c]
          + 0.5f*(inS[(size_t)bnS[2*i]*NCH+c] + inS[(size_t)bnS[2*i+1]*NCH+c]);
    }
  }
}

// ---------------- pixel-side kernels ----------------

__global__ void softmax_init_kernel(const float* __restrict__ U, __half* __restrict__ Qh) {
  int n = blockIdx.x*blockDim.x + threadIdx.x;
  if (n >= NPIX) return;
  float l[NCH];
  float m = -3.4e38f;
  #pragma unroll
  for (int c = 0; c < NCH; ++c) { l[c] = -U[(size_t)n*NCH+c]; m = fmaxf(m, l[c]); }
  float s = 0.f;
  #pragma unroll
  for (int c = 0; c < NCH; ++c) { l[c] = expf(l[c]-m); s += l[c]; }
  float r = 1.0f/s;
  #pragma unroll
  for (int c = 0; c < NCH; ++c) Qh[(size_t)n*QSH+c] = __float2half(l[c]*r);
}

template<bool FINAL>
__global__ void slice_combine_softmax_kernel(
    const float* __restrict__ U,
    const float* __restrict__ vb, const float* __restrict__ vs,
    const float* __restrict__ ws_b, const int* __restrict__ os_b,
    const float* __restrict__ ws_s, const int* __restrict__ os_s,
    const float* __restrict__ inv_nb, const float* __restrict__ inv_ns,
    float* __restrict__ QoutF, __half* __restrict__ QoutH,
    float scale_b, float scale_s) {
  int n = blockIdx.x*blockDim.x + threadIdx.x;
  if (n >= NPIX) return;
  float l[NCH];
  #pragma unroll
  for (int c = 0; c < NCH; ++c) l[c] = -U[(size_t)n*NCH+c];
  float fb = scale_b * inv_nb[n];
  #pragma unroll
  for (int j = 0; j < 6; ++j) {
    float w = fb * ws_b[n*6+j];
    const float* v = vb + (size_t)(os_b[n*6+j]+1)*NCH;
    #pragma unroll
    for (int c = 0; c < NCH; ++c) l[c] += w*v[c];
  }
  float fs = scale_s * inv_ns[n];
  #pragma unroll
  for (int j = 0; j < 3; ++j) {
    float w = fs * ws_s[n*3+j];
    const float* v = vs + (size_t)(os_s[n*3+j]+1)*NCH;
    #pragma unroll
    for (int c = 0; c < NCH; ++c) l[c] += w*v[c];
  }
  float m = -3.4e38f;
  #pragma unroll
  for (int c = 0; c < NCH; ++c) m = fmaxf(m, l[c]);
  float s = 0.f;
  #pragma unroll
  for (int c = 0; c < NCH; ++c) { l[c] = expf(l[c]-m); s += l[c]; }
  float r = 1.0f/s;
  if (FINAL) {
    #pragma unroll
    for (int c = 0; c < NCH; ++c) QoutF[(size_t)n*NCH+c] = l[c]*r;
  } else {
    #pragma unroll
    for (int c = 0; c < NCH; ++c) QoutH[(size_t)n*QSH+c] = __float2half(l[c]*r);
  }
}

// ---------------- host ----------------

extern "C" void kernel_launch(void* const* d_in, const int* in_sizes, int n_in,
                              void* d_out, int out_size, void* d_ws, size_t ws_size,
                              hipStream_t stream) {
  const float* U    = (const float*)d_in[0];
  const float* ws_b = (const float*)d_in[1];
  const float* ws_s = (const float*)d_in[2];
  const int*   os_b = (const int*)d_in[3];
  const int*   os_s = (const int*)d_in[4];
  const int*   bn_b = (const int*)d_in[5];
  const int*   bn_s = (const int*)d_in[6];
  const int Mb = in_sizes[5] / 12;
  const int Ms = in_sizes[6] / 6;
  const int Mtot = Mb + Ms;
  const int npb = NPIX*6, nps = NPIX*3;
  const int nptot = npb + nps;

  // workspace layout (16B-aligned chunks)
  char* wcur = (char*)d_ws;
  auto alloc = [&](size_t bytes) -> void* {
    void* p = (void*)wcur;
    wcur += (bytes + 15) & ~(size_t)15;
    return p;
  };
  __half* Qh    = (__half*)alloc((size_t)NPIX*QSH*2);
  float* vAb    = (float*)alloc((size_t)(Mb+1)*NCH*4);
  float* vBb    = (float*)alloc((size_t)(Mb+1)*NCH*4);
  float* vAs    = (float*)alloc((size_t)(Ms+1)*NCH*4);
  float* vBs    = (float*)alloc((size_t)(Ms+1)*NCH*4);
  float* inv_nb = (float*)alloc((size_t)NPIX*4);
  float* inv_ns = (float*)alloc((size_t)NPIX*4);
  int*   start  = (int*)alloc((size_t)(Mtot+1)*4);
  int*   cur    = (int*)alloc((size_t)Mtot*4);
  unsigned int* pw = (unsigned int*)alloc((size_t)nptot*4);
  int*   bsum   = (int*)alloc((size_t)(Mtot/256 + 2)*4);

  // norm-pass scalar fp32 buffers alias the (not yet used) multichannel buffers
  float* nb1a = vAb; float* nb1b = vAb + (Mb+1);
  float* ns1a = vAs; float* ns1b = vAs + (Ms+1);

  const int TB = 256;
  auto blocks = [](long long n){ return (int)((n + 255)/256); };

  const float a_b = 1.0f/(1.0f + 0.03125f);  // 1/(1+2^-5)
  const float a_s = 1.0f/(1.0f + 0.25f);     // 1/(1+2^-2)

  // ---- build unified CSR ----
  hipMemsetAsync(cur, 0, (size_t)Mtot*sizeof(int), stream);
  count_fused_kernel<<<blocks(nptot), TB, 0, stream>>>(os_b, os_s, cur, npb, nptot, Mb);
  scan_block_kernel<<<blocks(Mtot), 256, 0, stream>>>(cur, start, bsum, Mtot);
  scan_sums_kernel<<<1, 256, 0, stream>>>(bsum, blocks(Mtot));
  scan_add_kernel<<<blocks(Mtot+1), TB, 0, stream>>>(start, bsum, Mtot, nptot);
  hipMemsetAsync(cur, 0, (size_t)Mtot*sizeof(int), stream);
  fill_fused_kernel<<<blocks(nptot), TB, 0, stream>>>(os_b, ws_b, os_s, ws_s,
                                                      start, cur, pw, npb, nptot, Mb);

  // ---- normalization (C=1, fp32) ----
  hipMemsetAsync(nb1a, 0, sizeof(float), stream);
  hipMemsetAsync(nb1b, 0, sizeof(float), stream);
  hipMemsetAsync(ns1a, 0, sizeof(float), stream);
  hipMemsetAsync(ns1b, 0, sizeof(float), stream);
  gather_norm_kernel<<<blocks(Mtot), TB, 0, stream>>>(start, pw, nb1a, ns1a, Mb, Mtot);
  {
    float* ab = nb1a; float* bb = nb1b;
    float* as = ns1a; float* bs = ns1b;
    for (int j = 0; j < 6; ++j) {
      int ms = (j < 3) ? Ms : 0;
      blur1_fused_kernel<<<blocks(Mb + ms), TB, 0, stream>>>(
          ab, bb, bn_b + (size_t)j*Mb*2, Mb, as, bs, bn_s + (size_t)j*Ms*2, ms);
      { float* t = ab; ab = bb; bb = t; }
      if (j < 3) { float* t = as; as = bs; bs = t; }
    }
    slice_norm_fused_kernel<<<blocks(NPIX), TB, 0, stream>>>(
        ws_b, os_b, ws_s, os_s, ab, as, inv_nb, inv_ns, a_b, a_s);
  }

  // ---- zero sentinel row 0 of multichannel buffers ----
  hipMemsetAsync(vAb, 0, NCH*sizeof(float), stream);
  hipMemsetAsync(vBb, 0, NCH*sizeof(float), stream);
  hipMemsetAsync(vAs, 0, NCH*sizeof(float), stream);
  hipMemsetAsync(vBs, 0, NCH*sizeof(float), stream);

  softmax_init_kernel<<<blocks(NPIX), TB, 0, stream>>>(U, Qh);

  const float sb = 10.0f * a_b;  // BILATERAL_COMPAT * alpha_b
  const float ss = 3.0f * a_s;   // SPATIAL_COMPAT * alpha_s

  for (int it = 0; it < 5; ++it) {
    // fused gather splat (both lattices), wave per lattice point
    gather_wave_kernel<<<blocks((long long)Mtot*64), TB, 0, stream>>>(
        Qh, start, pw, vAb, vAs, Mb, Mtot);
    // fused blur chain: bilateral 6 steps, spatial first 3
    float* ab = vAb; float* bb = vBb;
    float* as = vAs; float* bs = vBs;
    for (int j = 0; j < 6; ++j) {
      int ms = (j < 3) ? Ms : 0;
      blurC_fused_kernel<<<blocks((long long)(Mb + ms)*NCH), TB, 0, stream>>>(
          ab, bb, bn_b + (size_t)j*Mb*2, Mb, as, bs, bn_s + (size_t)j*Ms*2, ms);
      { float* t = ab; ab = bb; bb = t; }
      if (j < 3) { float* t = as; as = bs; bs = t; }
    }
    // ab = final bilateral (vAb), as = final spatial (vBs)
    if (it == 4) {
      slice_combine_softmax_kernel<true><<<blocks(NPIX), TB, 0, stream>>>(
          U, ab, as, ws_b, os_b, ws_s, os_s, inv_nb, inv_ns,
          (float*)d_out, (__half*)nullptr, sb, ss);
    } else {
      slice_combine_softmax_kernel<false><<<blocks(NPIX), TB, 0, stream>>>(
          U, ab, as, ws_b, os_b, ws_s, os_s, inv_nb, inv_ns,
          (float*)nullptr, Qh, sb, ss);
    }
  }
}

// Round 6
// 491.272 us; speedup vs baseline: 42.5094x; 1.2848x over previous
//
#include <hip/hip_runtime.h>
#include <hip/hip_fp16.h>

#define NCH 21
#define NCH2 22         // 21 Q-channels + channel 21 = blurred weight-sum (norm)
#define VSH 32          // value row stride in halves (64B, one cache line)
#define QSH 32          // Q row stride in halves (64B, line-aligned)
#define NPIX (512*512)  // 2^18
#define DECODE (1.0f/(16383.f*128.f))   // w14 decode * 1/128 fp16 range guard

// ---------------- wave-aggregated atomic rank ----------------
__device__ __forceinline__ int wave_rank_atomic(int m, bool valid, int* __restrict__ cur) {
  int lane = threadIdx.x & 63;
  unsigned long long todo = __ballot(valid);
  int out = 0;
  while (todo) {
    int leader = __ffsll((unsigned long long)todo) - 1;
    int lm = __shfl(m, leader);
    unsigned long long match = __ballot(valid && (m == lm));
    int cnt = __popcll(match);
    int b = 0;
    if (lane == leader) b = atomicAdd(&cur[lm], cnt);
    b = __shfl(b, leader);
    if (valid && (m == lm)) {
      int rank = __popcll(match & ((1ull << lane) - 1ull));
      out = b + rank;
    }
    todo &= ~match;
  }
  return out;
}

// ---------------- unified CSR build ----------------

__global__ void count_fused_kernel(const int* __restrict__ os_b, const int* __restrict__ os_s,
                                   int* __restrict__ cnt, int npb, int nptot, int Mb) {
  int t = blockIdx.x*blockDim.x + threadIdx.x;
  bool valid = (t < nptot);
  int m = 0;
  if (valid) m = (t < npb) ? os_b[t] : (Mb + os_s[t - npb]);
  int lane = threadIdx.x & 63;
  unsigned long long todo = __ballot(valid);
  while (todo) {
    int leader = __ffsll((unsigned long long)todo) - 1;
    int lm = __shfl(m, leader);
    unsigned long long match = __ballot(valid && (m == lm));
    if (lane == leader) atomicAdd(&cnt[lm], __popcll(match));
    todo &= ~match;
  }
}

__global__ void scan_block_kernel(const int* __restrict__ cnt, int* __restrict__ excl,
                                  int* __restrict__ bsum, int M) {
  __shared__ int s[256];
  int i = blockIdx.x*256 + threadIdx.x;
  int v = (i < M) ? cnt[i] : 0;
  s[threadIdx.x] = v;
  __syncthreads();
  for (int off = 1; off < 256; off <<= 1) {
    int t = (threadIdx.x >= off) ? s[threadIdx.x - off] : 0;
    __syncthreads();
    s[threadIdx.x] += t;
    __syncthreads();
  }
  if (i < M) excl[i] = s[threadIdx.x] - v;
  if (threadIdx.x == 255) bsum[blockIdx.x] = s[255];
}

__global__ void scan_sums_kernel(int* __restrict__ bsum, int nb) {
  __shared__ int s[256];
  __shared__ int carry;
  if (threadIdx.x == 0) carry = 0;
  __syncthreads();
  for (int base = 0; base < nb; base += 256) {
    int i = base + threadIdx.x;
    int v = (i < nb) ? bsum[i] : 0;
    s[threadIdx.x] = v;
    __syncthreads();
    for (int off = 1; off < 256; off <<= 1) {
      int t = (threadIdx.x >= off) ? s[threadIdx.x - off] : 0;
      __syncthreads();
      s[threadIdx.x] += t;
      __syncthreads();
    }
    if (i < nb) bsum[i] = s[threadIdx.x] - v + carry;
    int tot = s[255];
    __syncthreads();
    if (threadIdx.x == 0) carry += tot;
    __syncthreads();
  }
}

__global__ void scan_add_kernel(int* __restrict__ excl, const int* __restrict__ bsum,
                                int M, int nptot) {
  int i = blockIdx.x*blockDim.x + threadIdx.x;
  if (i < M) excl[i] += bsum[i >> 8];
  else if (i == M) excl[M] = nptot;
}

__global__ void fill_fused_kernel(const int* __restrict__ os_b, const float* __restrict__ ws_b,
                                  const int* __restrict__ os_s, const float* __restrict__ ws_s,
                                  const int* __restrict__ start, int* __restrict__ cur,
                                  unsigned int* __restrict__ pw, int npb, int nptot, int Mb) {
  int t = blockIdx.x*blockDim.x + threadIdx.x;
  bool valid = (t < nptot);
  int m = 0, pix = 0; float w = 0.f;
  if (valid) {
    if (t < npb) { m = os_b[t]; pix = t / 6; w = ws_b[t]; }
    else { int t2 = t - npb; m = Mb + os_s[t2]; pix = t2 / 3; w = ws_s[t2]; }
  }
  int slot = wave_rank_atomic(m, valid, cur);
  if (valid) {
    int w14 = (int)(w * 16383.f + 0.5f);
    w14 = w14 < 0 ? 0 : (w14 > 16383 ? 16383 : w14);
    pw[start[m] + slot] = ((unsigned int)pix << 14) | (unsigned int)w14;
  }
}

// ---------------- lattice ops ----------------

// fused gather splat, wave-per-lattice-point: 3 pair-groups x 21 channels,
// channel 21 = weight sum (norm filter input), rides along for free.
__global__ void gather_wave_kernel(const __half* __restrict__ Qh, const int* __restrict__ start,
                                   const unsigned int* __restrict__ pw,
                                   __half* __restrict__ valsB, __half* __restrict__ valsS,
                                   int Mb, int Mtot) {
  int wid = blockIdx.x*(blockDim.x >> 6) + (threadIdx.x >> 6);
  if (wid >= Mtot) return;
  int lane = threadIdx.x & 63;
  int pg = lane / 21;          // 0,1,2 (lane 63 idle)
  int c  = lane - pg*21;
  float s = 0.f, wsum = 0.f;
  int k1 = start[wid+1];
  if (pg < 3) {
    int k = start[wid] + pg;
    for (; k + 9 < k1; k += 12) {
      unsigned int a0 = pw[k], a1 = pw[k+3], a2 = pw[k+6], a3 = pw[k+9];
      float w0 = (float)(a0 & 16383u), w1 = (float)(a1 & 16383u);
      float w2 = (float)(a2 & 16383u), w3 = (float)(a3 & 16383u);
      s += w0 * __half2float(Qh[((size_t)(a0 >> 14) << 5) + c])
         + w1 * __half2float(Qh[((size_t)(a1 >> 14) << 5) + c])
         + w2 * __half2float(Qh[((size_t)(a2 >> 14) << 5) + c])
         + w3 * __half2float(Qh[((size_t)(a3 >> 14) << 5) + c]);
      wsum += w0 + w1 + w2 + w3;
    }
    for (; k < k1; k += 3) {
      unsigned int a = pw[k];
      float w = (float)(a & 16383u);
      s += w * __half2float(Qh[((size_t)(a >> 14) << 5) + c]);
      wsum += w;
    }
  }
  // per-channel reduce across the 3 groups (valid for lanes 0..20)
  float s1 = __shfl(s, (lane + 21) & 63);
  float s2 = __shfl(s, (lane + 42) & 63);
  // weight-sum reduce (group partials identical within a group)
  float wt = __shfl(wsum, 0) + __shfl(wsum, 21) + __shfl(wsum, 42);
  __half* row = (wid < Mb) ? (valsB + (size_t)(wid+1)*VSH)
                           : (valsS + (size_t)(wid-Mb+1)*VSH);
  if (lane < 21)       row[c]  = __float2half((s + s1 + s2) * DECODE);
  else if (lane == 21) row[21] = __float2half(wt * DECODE);
}

// blur on fp16 rows, half2 chunks (11 chunks = 22 channels), fp32 math
__global__ void blurH_fused_kernel(const __half* __restrict__ inB, __half* __restrict__ outB,
                                   const int* __restrict__ bnB, int Mb,
                                   const __half* __restrict__ inS, __half* __restrict__ outS,
                                   const int* __restrict__ bnS, int Ms) {
  int t = blockIdx.x*blockDim.x + threadIdx.x;
  const __half* in; __half* out; const int* bn; int i, j;
  int tb = Mb*11;
  if (t < tb) { i = t/11; j = t - i*11; in = inB; out = outB; bn = bnB; }
  else {
    int t2 = t - tb;
    if (t2 >= Ms*11) return;
    i = t2/11; j = t2 - i*11; in = inS; out = outS; bn = bnS;
  }
  int b0 = bn[2*i], b1 = bn[2*i+1];
  float2 a = __half22float2(((const __half2*)(in + (size_t)(i+1)*VSH))[j]);
  float2 x = __half22float2(((const __half2*)(in + (size_t)b0*VSH))[j]);
  float2 y = __half22float2(((const __half2*)(in + (size_t)b1*VSH))[j]);
  float2 o;
  o.x = a.x + 0.5f*(x.x + y.x);
  o.y = a.y + 0.5f*(x.y + y.y);
  ((__half2*)(out + (size_t)(i+1)*VSH))[j] = __float22half2_rn(o);
}

// ---------------- pixel-side kernels ----------------

__global__ void softmax_init_kernel(const float* __restrict__ U, __half* __restrict__ Qh) {
  int n = blockIdx.x*blockDim.x + threadIdx.x;
  if (n >= NPIX) return;
  float l[NCH];
  float m = -3.4e38f;
  #pragma unroll
  for (int c = 0; c < NCH; ++c) { l[c] = -U[(size_t)n*NCH+c]; m = fmaxf(m, l[c]); }
  float s = 0.f;
  #pragma unroll
  for (int c = 0; c < NCH; ++c) { l[c] = expf(l[c]-m); s += l[c]; }
  float r = 1.0f/s;
  #pragma unroll
  for (int c = 0; c < NCH; ++c) Qh[(size_t)n*QSH+c] = __float2half(l[c]*r);
}

// slice both lattices + combine + softmax; norm = channel 21 ratio (alphas cancel)
template<bool FINAL>
__global__ void slice_combine_softmax_kernel(
    const float* __restrict__ U,
    const __half* __restrict__ vb, const __half* __restrict__ vs,
    const float* __restrict__ ws_b, const int* __restrict__ os_b,
    const float* __restrict__ ws_s, const int* __restrict__ os_s,
    float* __restrict__ QoutF, __half* __restrict__ QoutH) {
  int n = blockIdx.x*blockDim.x + threadIdx.x;
  if (n >= NPIX) return;
  float l[NCH];
  #pragma unroll
  for (int c = 0; c < NCH; ++c) l[c] = -U[(size_t)n*NCH+c];
  float acc[NCH2];
  #pragma unroll
  for (int c = 0; c < NCH2; ++c) acc[c] = 0.f;
  #pragma unroll
  for (int j = 0; j < 6; ++j) {
    float w = ws_b[n*6+j];
    const __half* v = vb + (size_t)(os_b[n*6+j]+1)*VSH;
    #pragma unroll
    for (int c = 0; c < NCH2; ++c) acc[c] += w*__half2float(v[c]);
  }
  float rb = 10.0f/(acc[NCH] + 1e-12f);   // BILATERAL_COMPAT / norm
  #pragma unroll
  for (int c = 0; c < NCH; ++c) l[c] += rb*acc[c];
  #pragma unroll
  for (int c = 0; c < NCH2; ++c) acc[c] = 0.f;
  #pragma unroll
  for (int j = 0; j < 3; ++j) {
    float w = ws_s[n*3+j];
    const __half* v = vs + (size_t)(os_s[n*3+j]+1)*VSH;
    #pragma unroll
    for (int c = 0; c < NCH2; ++c) acc[c] += w*__half2float(v[c]);
  }
  float rs = 3.0f/(acc[NCH] + 1e-12f);    // SPATIAL_COMPAT / norm
  #pragma unroll
  for (int c = 0; c < NCH; ++c) l[c] += rs*acc[c];
  float m = -3.4e38f;
  #pragma unroll
  for (int c = 0; c < NCH; ++c) m = fmaxf(m, l[c]);
  float s = 0.f;
  #pragma unroll
  for (int c = 0; c < NCH; ++c) { l[c] = expf(l[c]-m); s += l[c]; }
  float r = 1.0f/s;
  if (FINAL) {
    #pragma unroll
    for (int c = 0; c < NCH; ++c) QoutF[(size_t)n*NCH+c] = l[c]*r;
  } else {
    #pragma unroll
    for (int c = 0; c < NCH; ++c) QoutH[(size_t)n*QSH+c] = __float2half(l[c]*r);
  }
}

// ---------------- host ----------------

extern "C" void kernel_launch(void* const* d_in, const int* in_sizes, int n_in,
                              void* d_out, int out_size, void* d_ws, size_t ws_size,
                              hipStream_t stream) {
  const float* U    = (const float*)d_in[0];
  const float* ws_b = (const float*)d_in[1];
  const float* ws_s = (const float*)d_in[2];
  const int*   os_b = (const int*)d_in[3];
  const int*   os_s = (const int*)d_in[4];
  const int*   bn_b = (const int*)d_in[5];
  const int*   bn_s = (const int*)d_in[6];
  const int Mb = in_sizes[5] / 12;
  const int Ms = in_sizes[6] / 6;
  const int Mtot = Mb + Ms;
  const int npb = NPIX*6, nps = NPIX*3;
  const int nptot = npb + nps;

  // workspace layout (64B-aligned chunks)
  char* wcur = (char*)d_ws;
  auto alloc = [&](size_t bytes) -> void* {
    void* p = (void*)wcur;
    wcur += (bytes + 63) & ~(size_t)63;
    return p;
  };
  __half* Qh    = (__half*)alloc((size_t)NPIX*QSH*2);
  __half* vAb   = (__half*)alloc((size_t)(Mb+1)*VSH*2);
  __half* vBb   = (__half*)alloc((size_t)(Mb+1)*VSH*2);
  __half* vAs   = (__half*)alloc((size_t)(Ms+1)*VSH*2);
  __half* vBs   = (__half*)alloc((size_t)(Ms+1)*VSH*2);
  int*   start  = (int*)alloc((size_t)(Mtot+1)*4);
  int*   cur    = (int*)alloc((size_t)Mtot*4);
  unsigned int* pw = (unsigned int*)alloc((size_t)nptot*4);
  int*   bsum   = (int*)alloc((size_t)(Mtot/256 + 2)*4);

  const int TB = 256;
  auto blocks = [](long long n){ return (int)((n + 255)/256); };

  // ---- build unified CSR ----
  hipMemsetAsync(cur, 0, (size_t)Mtot*sizeof(int), stream);
  count_fused_kernel<<<blocks(nptot), TB, 0, stream>>>(os_b, os_s, cur, npb, nptot, Mb);
  scan_block_kernel<<<blocks(Mtot), 256, 0, stream>>>(cur, start, bsum, Mtot);
  scan_sums_kernel<<<1, 256, 0, stream>>>(bsum, blocks(Mtot));
  scan_add_kernel<<<blocks(Mtot+1), TB, 0, stream>>>(start, bsum, Mtot, nptot);
  hipMemsetAsync(cur, 0, (size_t)Mtot*sizeof(int), stream);
  fill_fused_kernel<<<blocks(nptot), TB, 0, stream>>>(os_b, ws_b, os_s, ws_s,
                                                      start, cur, pw, npb, nptot, Mb);

  // ---- zero sentinel row 0 of value buffers (bn index 0 = missing neighbor) ----
  hipMemsetAsync(vAb, 0, VSH*2, stream);
  hipMemsetAsync(vBb, 0, VSH*2, stream);
  hipMemsetAsync(vAs, 0, VSH*2, stream);
  hipMemsetAsync(vBs, 0, VSH*2, stream);

  softmax_init_kernel<<<blocks(NPIX), TB, 0, stream>>>(U, Qh);

  for (int it = 0; it < 5; ++it) {
    // fused gather splat (both lattices), wave per lattice point
    gather_wave_kernel<<<blocks((long long)Mtot*64), TB, 0, stream>>>(
        Qh, start, pw, vAb, vAs, Mb, Mtot);
    // fused blur chain: bilateral 6 steps, spatial first 3 (half2 chunks)
    __half* ab = vAb; __half* bb = vBb;
    __half* as = vAs; __half* bs = vBs;
    for (int j = 0; j < 6; ++j) {
      int ms = (j < 3) ? Ms : 0;
      blurH_fused_kernel<<<blocks((long long)(Mb + ms)*11), TB, 0, stream>>>(
          ab, bb, bn_b + (size_t)j*Mb*2, Mb, as, bs, bn_s + (size_t)j*Ms*2, ms);
      { __half* t = ab; ab = bb; bb = t; }
      if (j < 3) { __half* t = as; as = bs; bs = t; }
    }
    // ab = final bilateral (vAb), as = final spatial (vBs)
    if (it == 4) {
      slice_combine_softmax_kernel<true><<<blocks(NPIX), TB, 0, stream>>>(
          U, ab, as, ws_b, os_b, ws_s, os_s, (float*)d_out, (__half*)nullptr);
    } else {
      slice_combine_softmax_kernel<false><<<blocks(NPIX), TB, 0, stream>>>(
          U, ab, as, ws_b, os_b, ws_s, os_s, (float*)nullptr, Qh);
    }
  }
}